// Round 1
// baseline (1483.345 us; speedup 1.0000x reference)
//
#include <hip/hip_runtime.h>

// Problem: custom LSTM scan.  B=64, L=512, P=64, A=16, D=512, F=P+A=80.
//   ci  = tanh(x @ W_ci + b_ci)                  [B,L,D]   (parallel GEMM)
//   h_t = h_{t-1} + ci_t * sigmoid(h_{t-1} @ R_ig + b_ig)  (serial in t)
//   out = hs @ W_out + b_out                     [B,L,1]
//
// Design: one workgroup (512 threads) per batch row; R_ig converted to f16
// pairs and split: 36 uint4-blocks in VGPRs, 7 blocks in LDS, 21 blocks
// streamed from L2 each step.  Dots via v_dot2_f32_f16.  h kept fp32 in
// registers; packed f16 copy in LDS for broadcast.

#define B_  64
#define L_  512
#define P_  64
#define A_  16
#define D_  512
#define F_  80
#define CI_R 8

typedef _Float16 half2_t __attribute__((ext_vector_type(2)));

__device__ __forceinline__ float dot2(unsigned int r, unsigned int h, float acc) {
    return __builtin_amdgcn_fdot2(__builtin_bit_cast(half2_t, h),
                                  __builtin_bit_cast(half2_t, r), acc, false);
}
__device__ __forceinline__ float dot4(uint4 r, uint4 h, float acc) {
    acc = dot2(r.x, h.x, acc);
    acc = dot2(r.y, h.y, acc);
    acc = dot2(r.z, h.z, acc);
    acc = dot2(r.w, h.w, acc);
    return acc;
}

// Pack R_ig (fp32 [k][d]) into f16 pairs, tiled so that one uint4 at
// (k2b*512 + d) holds rows k = 8*k2b .. 8*k2b+7 of column d.
__global__ __launch_bounds__(256) void prep_kernel(const float* __restrict__ R,
                                                   unsigned int* __restrict__ Rp) {
    int u = blockIdx.x * 256 + threadIdx.x;    // [0, 64*512*4)
    int i = u & 3;
    int d = (u >> 2) & (D_ - 1);
    int k2b = u >> 11;
    int k0 = k2b * 8 + i * 2;
    half2_t v;
    v.x = (_Float16)R[k0 * D_ + d];
    v.y = (_Float16)R[(k0 + 1) * D_ + d];
    Rp[u] = __builtin_bit_cast(unsigned int, v);
}

// ci = tanh(x @ W_ci + b_ci), stored f16.  One block does 8 (b,l) rows.
__global__ __launch_bounds__(256) void ci_kernel(const float* __restrict__ obs,
                                                 const float* __restrict__ act,
                                                 const float* __restrict__ W,
                                                 const float* __restrict__ bci,
                                                 unsigned short* __restrict__ ci) {
    __shared__ float xs[CI_R][F_];
    int row0 = blockIdx.x * CI_R;
    int tid = threadIdx.x;
    for (int idx = tid; idx < CI_R * F_; idx += 256) {
        int r = idx / F_, f = idx % F_;
        float v = (f < P_) ? obs[(size_t)(row0 + r) * P_ + f]
                           : act[(size_t)(row0 + r) * A_ + (f - P_)];
        xs[r][f] = v;
    }
    __syncthreads();
    int d0 = tid, d1 = tid + 256;
    float a0[CI_R], a1[CI_R];
    #pragma unroll
    for (int r = 0; r < CI_R; ++r) { a0[r] = 0.f; a1[r] = 0.f; }
    for (int f = 0; f < F_; ++f) {
        float w0 = W[f * D_ + d0];
        float w1 = W[f * D_ + d1];
        #pragma unroll
        for (int r = 0; r < CI_R; ++r) {
            float xv = xs[r][f];
            a0[r] += xv * w0;
            a1[r] += xv * w1;
        }
    }
    float b0 = bci[d0], b1 = bci[d1];
    #pragma unroll
    for (int r = 0; r < CI_R; ++r) {
        float z0 = a0[r] + b0, z1 = a1[r] + b1;
        float e0 = __expf(-2.f * z0), e1 = __expf(-2.f * z1);
        float t0 = (1.f - e0) * __builtin_amdgcn_rcpf(1.f + e0);
        float t1 = (1.f - e1) * __builtin_amdgcn_rcpf(1.f + e1);
        ci[(size_t)(row0 + r) * D_ + d0] = __builtin_bit_cast(unsigned short, (_Float16)t0);
        ci[(size_t)(row0 + r) * D_ + d1] = __builtin_bit_cast(unsigned short, (_Float16)t1);
    }
}

// The serial scan.  One block per batch row, thread d owns column d.
// R blocks (uint4 each = 8 rows of one column): 0..35 registers,
// 36..42 LDS (56 KB), 43..63 streamed from L2 each step in 4 chunks.
__global__ __launch_bounds__(512, 2) void scan_kernel(
    const uint4* __restrict__ Rp, const unsigned short* __restrict__ ci,
    const float* __restrict__ b_ig, const float* __restrict__ W_out,
    const float* __restrict__ b_out, float* __restrict__ out)
{
    const int d = threadIdx.x;
    const int b = blockIdx.x;
    const int lane = d & 63;
    const int wv = d >> 6;

    __shared__ uint4 ldsR[7 * D_];
    __shared__ __align__(16) unsigned int hp[D_ / 2];  // packed f16 h
    __shared__ float red[8];

    uint4 rr[36];
    #pragma unroll
    for (int i = 0; i < 36; ++i) rr[i] = Rp[i * D_ + d];
    #pragma unroll
    for (int i = 0; i < 7; ++i) ldsR[i * D_ + d] = Rp[(36 + i) * D_ + d];
    if (d < D_ / 2) hp[d] = 0u;

    float hval = 0.f;                 // h[d], persistent fp32
    const float bg = b_ig[d];
    const float wo = W_out[d];
    const float bo = b_out[0];
    const unsigned short* cip = ci + (size_t)b * L_ * D_ + d;
    float* outp = out + b * L_;
    __syncthreads();

    const uint4* hp4 = (const uint4*)hp;

    for (int t = 0; t < L_; ++t) {
        uint4 s1[6], s2[5], s3[5], s4[5];
        #pragma unroll
        for (int i = 0; i < 6; ++i) s1[i] = Rp[(43 + i) * D_ + d];
        unsigned short cu = cip[t * D_];

        float acc0 = 0.f, acc1 = 0.f;
        #pragma unroll
        for (int i = 0; i < 18; i += 2) {
            acc0 = dot4(rr[i], hp4[i], acc0);
            acc1 = dot4(rr[i + 1], hp4[i + 1], acc1);
        }
        #pragma unroll
        for (int i = 0; i < 5; ++i) s2[i] = Rp[(49 + i) * D_ + d];
        #pragma unroll
        for (int i = 18; i < 36; i += 2) {
            acc0 = dot4(rr[i], hp4[i], acc0);
            acc1 = dot4(rr[i + 1], hp4[i + 1], acc1);
        }
        #pragma unroll
        for (int i = 0; i < 7; ++i) {
            uint4 rv = ldsR[i * D_ + d];
            acc0 = dot4(rv, hp4[36 + i], acc0);
        }
        #pragma unroll
        for (int i = 0; i < 5; ++i) s3[i] = Rp[(54 + i) * D_ + d];
        #pragma unroll
        for (int i = 0; i < 6; ++i) acc1 = dot4(s1[i], hp4[43 + i], acc1);
        #pragma unroll
        for (int i = 0; i < 5; ++i) s4[i] = Rp[(59 + i) * D_ + d];
        #pragma unroll
        for (int i = 0; i < 5; ++i) acc0 = dot4(s2[i], hp4[49 + i], acc0);
        #pragma unroll
        for (int i = 0; i < 5; ++i) acc1 = dot4(s3[i], hp4[54 + i], acc1);
        #pragma unroll
        for (int i = 0; i < 5; ++i) acc0 = dot4(s4[i], hp4[59 + i], acc0);

        float z = acc0 + acc1 + bg;
        float ig = __builtin_amdgcn_rcpf(1.f + __expf(-z));
        float civ = (float)__builtin_bit_cast(_Float16, cu);
        hval += civ * ig;
        float p = hval * wo;

        __syncthreads();   // everyone done reading old hp
        ((unsigned short*)hp)[d] = __builtin_bit_cast(unsigned short, (_Float16)hval);
        #pragma unroll
        for (int off = 32; off; off >>= 1) p += __shfl_xor(p, off, 64);
        if (lane == 0) red[wv] = p;
        __syncthreads();   // new hp + partials visible
        if (d == 0) {
            outp[t] = red[0] + red[1] + red[2] + red[3] +
                      red[4] + red[5] + red[6] + red[7] + bo;
        }
    }
}

extern "C" void kernel_launch(void* const* d_in, const int* in_sizes, int n_in,
                              void* d_out, int out_size, void* d_ws, size_t ws_size,
                              hipStream_t stream) {
    const float* obs   = (const float*)d_in[0];
    const float* act   = (const float*)d_in[1];
    const float* W_ci  = (const float*)d_in[2];
    const float* b_ci  = (const float*)d_in[3];
    const float* R_ig  = (const float*)d_in[4];
    const float* b_ig  = (const float*)d_in[5];
    const float* W_out = (const float*)d_in[6];
    const float* b_out = (const float*)d_in[7];
    float* out = (float*)d_out;

    unsigned short* ci = (unsigned short*)d_ws;                       // 32 MB f16
    unsigned int* Rp = (unsigned int*)((char*)d_ws + (size_t)B_ * L_ * D_ * 2);

    prep_kernel<<<(64 * D_ * 4) / 256, 256, 0, stream>>>(R_ig, Rp);
    ci_kernel<<<(B_ * L_) / CI_R, 256, 0, stream>>>(obs, act, W_ci, b_ci, ci);
    scan_kernel<<<B_, D_, 0, stream>>>((const uint4*)Rp, ci, b_ig, W_out, b_out, out);
}

// Round 3
// 1434.472 us; speedup vs baseline: 1.0341x; 1.0341x over previous
//
#include <hip/hip_runtime.h>

// Custom LSTM scan.  B=64, L=512, P=64, A=16, D=512, F=80.
//   h_t = h_{t-1} + tanh(x_t W_ci + b_ci) * sigmoid(h_{t-1} R_ig + b_ig)
// Scan kernel: one WG (512 thr) per batch row.  Output d computed by 8 lanes
// (k-slices of 64) reduced via DPP; R_ig as f16 pairs split 36 reg / 7 LDS /
// 21 L2-streamed uint4 chunks per thread.  h broadcast as packed f16 in LDS.

#define B_  64
#define L_  512
#define P_  64
#define A_  16
#define D_  512
#define F_  80
#define CI_R 32

typedef _Float16 half2_t __attribute__((ext_vector_type(2)));

__device__ __forceinline__ float dot2(unsigned int r, unsigned int h, float acc) {
    return __builtin_amdgcn_fdot2(__builtin_bit_cast(half2_t, h),
                                  __builtin_bit_cast(half2_t, r), acc, false);
}
__device__ __forceinline__ float dot4u(uint4 r, uint4 h, float acc) {
    acc = dot2(r.x, h.x, acc);
    acc = dot2(r.y, h.y, acc);
    acc = dot2(r.z, h.z, acc);
    acc = dot2(r.w, h.w, acc);
    return acc;
}
template<int CTRL>
__device__ __forceinline__ float dpp_mov(float v) {
    return __builtin_bit_cast(float, __builtin_amdgcn_update_dpp(
        0, __builtin_bit_cast(int, v), CTRL, 0xF, 0xF, true));
}
// DPP ctrls: quad_perm(1,0,3,2)=0xB1 (xor1), quad_perm(2,3,0,1)=0x4E (xor2),
// row_half_mirror=0x141 (xor7), row_mirror=0x140 (xor15),
// row_bcast15=0x142, row_bcast31=0x143.

// Pack R_ig fp32[k][d] -> f16-pair uint chunks laid out [w][j][c][l][q]:
// uint4 (w,j,c,l) holds pairs p = g*32+c*4+{0..3} (k=2p,2p+1) of column
// d = w*64 + (l>>3)*8 + j, where g = l&7.
__global__ __launch_bounds__(256) void prep_kernel(const float* __restrict__ R,
                                                   unsigned int* __restrict__ Rp) {
    int id = blockIdx.x * 256 + threadIdx.x;          // 131072 uints
    int q = id & 3;
    int l = (id >> 2) & 63;
    int c = (id >> 8) & 7;
    int j = (id >> 11) & 7;
    int w = id >> 14;
    int r = l >> 3, g = l & 7;
    int d = w * 64 + r * 8 + j;
    int p = g * 32 + c * 4 + q;
    int k0 = 2 * p;
    half2_t v;
    v.x = (_Float16)R[k0 * D_ + d];
    v.y = (_Float16)R[(k0 + 1) * D_ + d];
    Rp[id] = __builtin_bit_cast(unsigned int, v);
}

// ci = tanh(x @ W_ci + b_ci), stored f16.  One block does 32 (b,l) rows.
__global__ __launch_bounds__(256) void ci_kernel(const float* __restrict__ obs,
                                                 const float* __restrict__ act,
                                                 const float* __restrict__ W,
                                                 const float* __restrict__ bci,
                                                 unsigned short* __restrict__ ci) {
    __shared__ float xs[CI_R][F_];
    int row0 = blockIdx.x * CI_R;
    int tid = threadIdx.x;
    for (int idx = tid; idx < CI_R * F_; idx += 256) {
        int r = idx / F_, f = idx % F_;
        float v = (f < P_) ? obs[(size_t)(row0 + r) * P_ + f]
                           : act[(size_t)(row0 + r) * A_ + (f - P_)];
        xs[r][f] = v;
    }
    __syncthreads();
    int d0 = tid, d1 = tid + 256;
    float a0[CI_R], a1[CI_R];
    #pragma unroll
    for (int r = 0; r < CI_R; ++r) { a0[r] = 0.f; a1[r] = 0.f; }
    for (int f = 0; f < F_; ++f) {
        float w0 = W[f * D_ + d0];
        float w1 = W[f * D_ + d1];
        #pragma unroll
        for (int r = 0; r < CI_R; ++r) {
            float xv = xs[r][f];
            a0[r] += xv * w0;
            a1[r] += xv * w1;
        }
    }
    float b0 = bci[d0], b1 = bci[d1];
    #pragma unroll
    for (int r = 0; r < CI_R; ++r) {
        float z0 = a0[r] + b0, z1 = a1[r] + b1;
        // tanh via exp of negative magnitude (no overflow -> no NaN)
        float e0 = __expf(-2.f * __builtin_fabsf(z0));
        float e1 = __expf(-2.f * __builtin_fabsf(z1));
        float m0 = (1.f - e0) * __builtin_amdgcn_rcpf(1.f + e0);
        float m1 = (1.f - e1) * __builtin_amdgcn_rcpf(1.f + e1);
        float t0 = z0 < 0.f ? -m0 : m0;
        float t1 = z1 < 0.f ? -m1 : m1;
        ci[(size_t)(row0 + r) * D_ + d0] = __builtin_bit_cast(unsigned short, (_Float16)t0);
        ci[(size_t)(row0 + r) * D_ + d1] = __builtin_bit_cast(unsigned short, (_Float16)t1);
    }
}

// Serial scan.  One block per batch row.  Thread (w=tid>>6, l=tid&63):
// r=l>>3, g=l&7; computes partials over k in [g*64,g*64+64) for outputs
// d = w*64 + r*8 + j, j=0..7; DPP reduce-scatter leaves lane with j=g,
// i.e. thread owns d = tid.  R chunks jc=j*8+c: 0..35 regs, 36..42 LDS,
// 43..63 streamed from L2 (group A=43..53, B=54..63, shared buffer).
__global__ __launch_bounds__(512, 2) void scan_kernel(
    const uint4* __restrict__ Rp, const unsigned short* __restrict__ ci,
    const float* __restrict__ b_ig, const float* __restrict__ W_out,
    const float* __restrict__ b_out, float* __restrict__ out)
{
    const int tid = threadIdx.x;
    const int b = blockIdx.x;
    const int w = tid >> 6;
    const int l = tid & 63;
    const int g = l & 7;

    __shared__ uint4 ldsR[7 * D_];
    __shared__ __align__(16) unsigned int hp[D_ / 2];   // packed f16 h
    __shared__ float red[8];
    __shared__ float outbuf[L_];

    const uint4* tb = Rp + (w << 12) + l;   // [w][jc][l] chunks: tb[jc*64]

    uint4 rr[36];
    #pragma unroll
    for (int i = 0; i < 36; ++i) rr[i] = tb[i * 64];
    #pragma unroll
    for (int i = 0; i < 7; ++i) ldsR[i * D_ + tid] = tb[(36 + i) * 64];
    if (tid < 256) hp[tid] = 0u;

    float hval = 0.f;                      // h[tid], fp32, persistent
    const float bg = b_ig[tid];
    const float wo = W_out[tid];
    const float bo = b_out[0];
    const unsigned short* cip = ci + (size_t)b * L_ * D_ + tid;

    __syncthreads();

    const uint4* hp4 = (const uint4*)hp;

    #pragma unroll 1
    for (int t = 0; t < L_; ++t) {
        // issue stream group A (jc 43..53) + ci load early
        uint4 sb[11];
        #pragma unroll
        for (int i = 0; i < 11; ++i) sb[i] = tb[(43 + i) * 64];
        unsigned short cu = cip[t * D_];

        // h slice (64 values = 8 uint4), shared by all 8 outputs
        uint4 hsr[8];
        #pragma unroll
        for (int c = 0; c < 8; ++c) hsr[c] = hp4[g * 8 + c];

        float p[8];
        #pragma unroll
        for (int j = 0; j < 8; ++j) p[j] = 0.f;

        // register-resident: j=0..3 all c
        #pragma unroll
        for (int j = 0; j < 4; ++j)
            #pragma unroll
            for (int c = 0; c < 8; ++c)
                p[j] = dot4u(rr[j * 8 + c], hsr[c], p[j]);

        // consume A: jc43..47 -> p[5] (c=3..7); jc48..53 -> p[6] (c=0..5)
        #pragma unroll
        for (int i = 0; i < 5; ++i) p[5] = dot4u(sb[i], hsr[3 + i], p[5]);
        #pragma unroll
        for (int i = 0; i < 6; ++i) p[6] = dot4u(sb[5 + i], hsr[i], p[6]);

        // issue stream group B (jc 54..63) into reused buffers
        #pragma unroll
        for (int i = 0; i < 10; ++i) sb[i] = tb[(54 + i) * 64];

        // register-resident: j=4 c=0..3
        #pragma unroll
        for (int c = 0; c < 4; ++c)
            p[4] = dot4u(rr[32 + c], hsr[c], p[4]);
        // LDS-resident: jc36..39 -> p[4] (c=4..7); jc40..42 -> p[5] (c=0..2)
        #pragma unroll
        for (int i = 0; i < 4; ++i)
            p[4] = dot4u(ldsR[i * D_ + tid], hsr[4 + i], p[4]);
        #pragma unroll
        for (int i = 0; i < 3; ++i)
            p[5] = dot4u(ldsR[(4 + i) * D_ + tid], hsr[i], p[5]);

        // consume B: jc54,55 -> p[6] (c=6,7); jc56..63 -> p[7] (c=0..7)
        p[6] = dot4u(sb[0], hsr[6], p[6]);
        p[6] = dot4u(sb[1], hsr[7], p[6]);
        #pragma unroll
        for (int i = 0; i < 8; ++i) p[7] = dot4u(sb[2 + i], hsr[i], p[7]);

        // reduce-scatter over the 8-lane slice group (all DPP):
        // stage 1: xor7 (row_half_mirror), keep j&4==g&4
        float q0[4];
        #pragma unroll
        for (int i = 0; i < 4; ++i) {
            float a = p[i] + dpp_mov<0x141>(p[i]);
            float c2 = p[i + 4] + dpp_mov<0x141>(p[i + 4]);
            q0[i] = (g & 4) ? c2 : a;
        }
        // stage 2: xor1 (quad_perm), keep j&1==g&1
        float r0a = q0[0] + dpp_mov<0xB1>(q0[0]);
        float r0b = q0[1] + dpp_mov<0xB1>(q0[1]);
        float r1a = q0[2] + dpp_mov<0xB1>(q0[2]);
        float r1b = q0[3] + dpp_mov<0xB1>(q0[3]);
        float r0 = (g & 1) ? r0b : r0a;
        float r1 = (g & 1) ? r1b : r1a;
        // stage 3: xor2 (quad_perm), keep j&2==g&2
        float za = r0 + dpp_mov<0x4E>(r0);
        float zb = r1 + dpp_mov<0x4E>(r1);
        float z = (g & 2) ? zb : za;      // z for output d = tid

        float zz = z + bg;
        float ig = __builtin_amdgcn_rcpf(1.f + __expf(-zz));
        float civ = (float)__builtin_bit_cast(_Float16, cu);
        hval += civ * ig;

        // wave-reduce hval*wo via DPP (sum lands in lane 63)
        float po = hval * wo;
        po += dpp_mov<0xB1>(po);
        po += dpp_mov<0x4E>(po);
        po += dpp_mov<0x141>(po);
        po += dpp_mov<0x140>(po);
        po += dpp_mov<0x142>(po);
        po += dpp_mov<0x143>(po);

        float nbh = dpp_mov<0xB1>(hval);  // neighbor (lane^1) h, all lanes active

        __syncthreads();                  // all reads of old hp complete
        if ((tid & 1) == 0) {
            hp[tid >> 1] = __builtin_bit_cast(unsigned int,
                               __builtin_amdgcn_cvt_pkrtz(hval, nbh));
        }
        if (l == 63) red[w] = po;
        __syncthreads();                  // new hp + partials visible
        if (tid == 0) {
            outbuf[t] = red[0] + red[1] + red[2] + red[3] +
                        red[4] + red[5] + red[6] + red[7] + bo;
        }
    }
    __syncthreads();
    out[b * L_ + tid] = outbuf[tid];
}

extern "C" void kernel_launch(void* const* d_in, const int* in_sizes, int n_in,
                              void* d_out, int out_size, void* d_ws, size_t ws_size,
                              hipStream_t stream) {
    const float* obs   = (const float*)d_in[0];
    const float* act   = (const float*)d_in[1];
    const float* W_ci  = (const float*)d_in[2];
    const float* b_ci  = (const float*)d_in[3];
    const float* R_ig  = (const float*)d_in[4];
    const float* b_ig  = (const float*)d_in[5];
    const float* W_out = (const float*)d_in[6];
    const float* b_out = (const float*)d_in[7];
    float* out = (float*)d_out;

    unsigned short* ci = (unsigned short*)d_ws;                        // 32 MB f16
    unsigned int* Rp = (unsigned int*)((char*)d_ws + (size_t)B_ * L_ * D_ * 2);

    prep_kernel<<<512, 256, 0, stream>>>(R_ig, Rp);
    ci_kernel<<<(B_ * L_) / CI_R, 256, 0, stream>>>(obs, act, W_ci, b_ci, ci);
    scan_kernel<<<B_, D_, 0, stream>>>((const uint4*)Rp, ci, b_ig, W_out, b_out, out);
}